// Round 1
// baseline (1028.616 us; speedup 1.0000x reference)
//
#include <hip/hip_runtime.h>

#define DEVI __device__ __forceinline__

typedef short v8s __attribute__((ext_vector_type(8)));
typedef float v4f __attribute__((ext_vector_type(4)));
typedef unsigned short u16;

DEVI float bf2f(short s) {
  union { unsigned u; float f; } cv;
  cv.u = ((unsigned)(u16)s) << 16;
  return cv.f;
}
DEVI short f2bf(float f) {
  union { float f; unsigned u; } cv; cv.f = f;
  unsigned u = cv.u;
  return (short)((u + 0x7FFFu + ((u >> 16) & 1u)) >> 16);
}

// ---------------- prep: transpose + cast weights to bf16 ----------------
// WcT[768][256]: rows 0..255 = Wq^T, 256..511 = Wk^T, 512..767 = Wv^T
// WoT[256][256] = Wout^T
__global__ void prep_weights(const float* __restrict__ Wq, const float* __restrict__ Wk,
                             const float* __restrict__ Wv, const float* __restrict__ Wout,
                             short* __restrict__ WcT, short* __restrict__ WoT) {
  int n = blockIdx.x;
  int k = threadIdx.x;
  float v;
  if (n < 256)      v = Wq[k * 256 + n];
  else if (n < 512) v = Wk[k * 256 + (n - 256)];
  else              v = Wv[k * 256 + (n - 512)];
  WcT[n * 256 + k] = f2bf(v);
  if (n < 256) WoT[n * 256 + k] = f2bf(Wout[k * 256 + n]);
}

// ---------------- QKV projection GEMM (A fp32 -> bf16 MFMA) ----------------
// C[131072][768] ; tile 128x128, BK=64, 4 waves (2x2), wave tile 64x64 (4x4 frags)
__launch_bounds__(256, 2)
__global__ void proj_gemm(const float* __restrict__ x, const short* __restrict__ WcT,
                          const float* __restrict__ pos_emb,
                          short* __restrict__ Qb, short* __restrict__ Kb,
                          short* __restrict__ Vb) {
  __shared__ short As[128 * 64];
  __shared__ short Bs[128 * 64];
  const int t = threadIdx.x;
  const int m0 = blockIdx.x * 128;
  const int n0 = blockIdx.y * 128;
  const int wave = t >> 6, lane = t & 63;
  const int wm = (wave & 1) * 64, wn = (wave >> 1) * 64;
  const int lr = lane & 15, g = lane >> 4;

  v4f zero = {0.f, 0.f, 0.f, 0.f};
  v4f acc[4][4];
#pragma unroll
  for (int i = 0; i < 4; ++i)
#pragma unroll
    for (int j = 0; j < 4; ++j) acc[i][j] = zero;

  for (int kt = 0; kt < 256; kt += 64) {
    if (kt) __syncthreads();
    // stage A: 128 rows x 64 k, fp32 -> bf16, swizzled [row][k]
#pragma unroll
    for (int i = 0; i < 8; ++i) {
      int idx = t + i * 256;
      int row = idx >> 4, c4 = idx & 15;
      const float4 vv = *reinterpret_cast<const float4*>(x + (size_t)(m0 + row) * 256 + kt + c4 * 4);
      short4 pk;
      pk.x = f2bf(vv.x); pk.y = f2bf(vv.y); pk.z = f2bf(vv.z); pk.w = f2bf(vv.w);
      int byte = (row * 128 + c4 * 8) ^ ((row & 7) << 4);
      *reinterpret_cast<short4*>(reinterpret_cast<char*>(As) + byte) = pk;
    }
    // stage B: 128 n-rows x 64 k (WcT is [n][k]) bf16, swizzled
#pragma unroll
    for (int i = 0; i < 4; ++i) {
      int idx = t + i * 256;
      int rn = idx >> 3, c = idx & 7;
      v8s vv = *reinterpret_cast<const v8s*>(WcT + (size_t)(n0 + rn) * 256 + kt + c * 8);
      int byte = (rn * 128 + c * 16) ^ ((rn & 7) << 4);
      *reinterpret_cast<v8s*>(reinterpret_cast<char*>(Bs) + byte) = vv;
    }
    __syncthreads();
#pragma unroll
    for (int kk = 0; kk < 2; ++kk) {
      v8s af[4], bfr[4];
#pragma unroll
      for (int i = 0; i < 4; ++i) {
        int row = wm + i * 16 + lr;
        int byte = (row * 128 + kk * 64 + g * 16) ^ ((row & 7) << 4);
        af[i] = *reinterpret_cast<const v8s*>(reinterpret_cast<const char*>(As) + byte);
      }
#pragma unroll
      for (int j = 0; j < 4; ++j) {
        int rn = wn + j * 16 + lr;
        int byte = (rn * 128 + kk * 64 + g * 16) ^ ((rn & 7) << 4);
        bfr[j] = *reinterpret_cast<const v8s*>(reinterpret_cast<const char*>(Bs) + byte);
      }
#pragma unroll
      for (int i = 0; i < 4; ++i)
#pragma unroll
        for (int j = 0; j < 4; ++j)
          acc[i][j] = __builtin_amdgcn_mfma_f32_16x16x32_bf16(af[i], bfr[j], acc[i][j], 0, 0, 0);
    }
  }
  // epilogue: C/D frag layout col=lane&15, row=(lane>>4)*4+r
#pragma unroll
  for (int i = 0; i < 4; ++i) {
#pragma unroll
    for (int j = 0; j < 4; ++j) {
      int colg = n0 + wn + j * 16 + lr;
#pragma unroll
      for (int r = 0; r < 4; ++r) {
        int p = m0 + wm + i * 16 + g * 4 + r;
        float v = acc[i][j][r];
        if (colg < 256) {
          int yy = (p >> 7) & 127, xx = p & 127;
          int qi = (yy - min(max(yy, 2), 125) + 2) * 5 + (xx - min(max(xx, 2), 125) + 2);
          v += pos_emb[qi * 256 + colg];
          Qb[(size_t)p * 256 + colg] = f2bf(v);
        } else if (colg < 512) {
          Kb[(size_t)p * 256 + (colg - 256)] = f2bf(v);
        } else {
          Vb[(size_t)p * 256 + (colg - 512)] = f2bf(v);
        }
      }
    }
  }
}

// ---------------- attention: scores + softmax + PV ----------------
// thread = (position, head); block = 8y x 4x positions * 8 heads = 256 threads
__global__ void attn_kernel(const short* __restrict__ Qb, const short* __restrict__ Kb,
                            const short* __restrict__ Vb, const float* __restrict__ pos_emb,
                            short* __restrict__ ACC) {
  __shared__ float pe[25 * 256];
  for (int i = threadIdx.x; i < 25 * 256; i += 256) {
    int f = i & 255;
    int dst = (i & ~255) + (f ^ ((f >> 5) << 2));  // bank-deconflict swizzle
    pe[dst] = pos_emb[i];
  }
  __syncthreads();
  const int t = threadIdx.x;
  const int h = t & 7, pi = t >> 3;
  const int xx = blockIdx.x * 4 + (pi & 3);
  const int yy = blockIdx.y * 8 + (pi >> 2);
  const int b = blockIdx.z;
  const int yc = min(max(yy, 2), 125), xc = min(max(xx, 2), 125);
  const int hb = h * 32;
  const int hx4 = h << 2;
  const size_t pbase = ((size_t)((b * 128 + yy) * 128 + xx)) * 256 + hb;

  float q[32];
  {
    const v8s* qp = reinterpret_cast<const v8s*>(Qb + pbase);
#pragma unroll
    for (int c = 0; c < 4; ++c) {
      v8s qv = qp[c];
#pragma unroll
      for (int e = 0; e < 8; ++e) q[c * 8 + e] = bf2f(qv[e]);
    }
  }

  float sc[25];
#pragma unroll
  for (int s = 0; s < 25; ++s) {
    const int ny = yc + s / 5 - 2, nx = xc + s % 5 - 2;
    const v8s* kp = reinterpret_cast<const v8s*>(Kb + ((size_t)((b * 128 + ny) * 128 + nx)) * 256 + hb);
    const float* peb = &pe[s * 256];
    float dot = 0.f;
#pragma unroll
    for (int c = 0; c < 4; ++c) {
      v8s kv = kp[c];
      float4 p0 = *reinterpret_cast<const float4*>(peb + (((hb + c * 8)) ^ hx4));
      float4 p1 = *reinterpret_cast<const float4*>(peb + (((hb + c * 8 + 4)) ^ hx4));
      dot = fmaf(q[c * 8 + 0], bf2f(kv[0]) + p0.x, dot);
      dot = fmaf(q[c * 8 + 1], bf2f(kv[1]) + p0.y, dot);
      dot = fmaf(q[c * 8 + 2], bf2f(kv[2]) + p0.z, dot);
      dot = fmaf(q[c * 8 + 3], bf2f(kv[3]) + p0.w, dot);
      dot = fmaf(q[c * 8 + 4], bf2f(kv[4]) + p1.x, dot);
      dot = fmaf(q[c * 8 + 5], bf2f(kv[5]) + p1.y, dot);
      dot = fmaf(q[c * 8 + 6], bf2f(kv[6]) + p1.z, dot);
      dot = fmaf(q[c * 8 + 7], bf2f(kv[7]) + p1.w, dot);
    }
    sc[s] = dot * 0.17677669529663689f;  // 1/sqrt(32)
  }

  float m = sc[0];
#pragma unroll
  for (int s = 1; s < 25; ++s) m = fmaxf(m, sc[s]);
  float l = 0.f;
#pragma unroll
  for (int s = 0; s < 25; ++s) {
    float e = __expf(sc[s] - m);
    sc[s] = e;
    l += e;
  }

  float oa[32];
#pragma unroll
  for (int f = 0; f < 32; ++f) oa[f] = 0.f;
#pragma unroll
  for (int s = 0; s < 25; ++s) {
    const int ny = yc + s / 5 - 2, nx = xc + s % 5 - 2;
    const v8s* vp = reinterpret_cast<const v8s*>(Vb + ((size_t)((b * 128 + ny) * 128 + nx)) * 256 + hb);
    float w = sc[s];
#pragma unroll
    for (int c = 0; c < 4; ++c) {
      v8s vv = vp[c];
#pragma unroll
      for (int e = 0; e < 8; ++e) oa[c * 8 + e] = fmaf(w, bf2f(vv[e]), oa[c * 8 + e]);
    }
  }
  float inv = 1.f / l;
  v8s* op = reinterpret_cast<v8s*>(ACC + pbase);
#pragma unroll
  for (int c = 0; c < 4; ++c) {
    v8s pk;
#pragma unroll
    for (int e = 0; e < 8; ++e) pk[e] = f2bf(oa[c * 8 + e] * inv);
    op[c] = pk;
  }
}

// ---------------- output projection GEMM (A bf16) ----------------
__launch_bounds__(256, 2)
__global__ void out_gemm(const short* __restrict__ A, const short* __restrict__ WoT,
                         float* __restrict__ out) {
  __shared__ short As[128 * 64];
  __shared__ short Bs[128 * 64];
  const int t = threadIdx.x;
  const int m0 = blockIdx.x * 128;
  const int n0 = blockIdx.y * 128;
  const int wave = t >> 6, lane = t & 63;
  const int wm = (wave & 1) * 64, wn = (wave >> 1) * 64;
  const int lr = lane & 15, g = lane >> 4;

  v4f zero = {0.f, 0.f, 0.f, 0.f};
  v4f acc[4][4];
#pragma unroll
  for (int i = 0; i < 4; ++i)
#pragma unroll
    for (int j = 0; j < 4; ++j) acc[i][j] = zero;

  for (int kt = 0; kt < 256; kt += 64) {
    if (kt) __syncthreads();
#pragma unroll
    for (int i = 0; i < 4; ++i) {
      int idx = t + i * 256;
      int row = idx >> 3, c = idx & 7;
      v8s vv = *reinterpret_cast<const v8s*>(A + (size_t)(m0 + row) * 256 + kt + c * 8);
      int byte = (row * 128 + c * 16) ^ ((row & 7) << 4);
      *reinterpret_cast<v8s*>(reinterpret_cast<char*>(As) + byte) = vv;
    }
#pragma unroll
    for (int i = 0; i < 4; ++i) {
      int idx = t + i * 256;
      int rn = idx >> 3, c = idx & 7;
      v8s vv = *reinterpret_cast<const v8s*>(WoT + (size_t)(n0 + rn) * 256 + kt + c * 8);
      int byte = (rn * 128 + c * 16) ^ ((rn & 7) << 4);
      *reinterpret_cast<v8s*>(reinterpret_cast<char*>(Bs) + byte) = vv;
    }
    __syncthreads();
#pragma unroll
    for (int kk = 0; kk < 2; ++kk) {
      v8s af[4], bfr[4];
#pragma unroll
      for (int i = 0; i < 4; ++i) {
        int row = wm + i * 16 + lr;
        int byte = (row * 128 + kk * 64 + g * 16) ^ ((row & 7) << 4);
        af[i] = *reinterpret_cast<const v8s*>(reinterpret_cast<const char*>(As) + byte);
      }
#pragma unroll
      for (int j = 0; j < 4; ++j) {
        int rn = wn + j * 16 + lr;
        int byte = (rn * 128 + kk * 64 + g * 16) ^ ((rn & 7) << 4);
        bfr[j] = *reinterpret_cast<const v8s*>(reinterpret_cast<const char*>(Bs) + byte);
      }
#pragma unroll
      for (int i = 0; i < 4; ++i)
#pragma unroll
        for (int j = 0; j < 4; ++j)
          acc[i][j] = __builtin_amdgcn_mfma_f32_16x16x32_bf16(af[i], bfr[j], acc[i][j], 0, 0, 0);
    }
  }
#pragma unroll
  for (int i = 0; i < 4; ++i) {
#pragma unroll
    for (int j = 0; j < 4; ++j) {
      int colg = n0 + wn + j * 16 + lr;
#pragma unroll
      for (int r = 0; r < 4; ++r) {
        int p = m0 + wm + i * 16 + g * 4 + r;
        out[(size_t)p * 256 + colg] = acc[i][j][r];
      }
    }
  }
}

extern "C" void kernel_launch(void* const* d_in, const int* in_sizes, int n_in,
                              void* d_out, int out_size, void* d_ws, size_t ws_size,
                              hipStream_t stream) {
  const float* x       = (const float*)d_in[0];
  const float* Wq      = (const float*)d_in[1];
  const float* Wk      = (const float*)d_in[2];
  const float* Wv      = (const float*)d_in[3];
  const float* Wout    = (const float*)d_in[4];
  const float* pos_emb = (const float*)d_in[5];
  float* out = (float*)d_out;

  char* ws = (char*)d_ws;
  short* WcT  = (short*)ws;                       // 768*256*2   = 393216 B
  short* WoT  = (short*)(ws + 393216);            // 256*256*2   = 131072 B
  short* Qb   = (short*)(ws + 524288);            // 131072*256*2 each
  short* Kb   = Qb + (size_t)131072 * 256;
  short* Vb   = Kb + (size_t)131072 * 256;
  short* ACCb = Vb + (size_t)131072 * 256;
  // total ws use: 524288 + 4*67108864 = 268,959,744 B

  prep_weights<<<768, 256, 0, stream>>>(Wq, Wk, Wv, Wout, WcT, WoT);
  proj_gemm<<<dim3(1024, 6), 256, 0, stream>>>(x, WcT, pos_emb, Qb, Kb, Vb);
  attn_kernel<<<dim3(32, 16, 8), 256, 0, stream>>>(Qb, Kb, Vb, pos_emb, ACCb);
  out_gemm<<<dim3(1024, 2), 256, 0, stream>>>(ACCb, WoT, out);
}

// Round 2
// 520.412 us; speedup vs baseline: 1.9765x; 1.9765x over previous
//
#include <hip/hip_runtime.h>

#define DEVI __device__ __forceinline__

typedef short v8s __attribute__((ext_vector_type(8)));
typedef float v4f __attribute__((ext_vector_type(4)));
typedef unsigned short u16;

DEVI float bf2f(short s) {
  union { unsigned u; float f; } cv;
  cv.u = ((unsigned)(u16)s) << 16;
  return cv.f;
}
DEVI short f2bf(float f) {
  union { float f; unsigned u; } cv; cv.f = f;
  unsigned u = cv.u;
  return (short)((u + 0x7FFFu + ((u >> 16) & 1u)) >> 16);
}

// ---------------- prep: transpose + cast weights to bf16 ----------------
__global__ void prep_weights(const float* __restrict__ Wq, const float* __restrict__ Wk,
                             const float* __restrict__ Wv, const float* __restrict__ Wout,
                             short* __restrict__ WcT, short* __restrict__ WoT) {
  int n = blockIdx.x;
  int k = threadIdx.x;
  float v;
  if (n < 256)      v = Wq[k * 256 + n];
  else if (n < 512) v = Wk[k * 256 + (n - 256)];
  else              v = Wv[k * 256 + (n - 512)];
  WcT[n * 256 + k] = f2bf(v);
  if (n < 256) WoT[n * 256 + k] = f2bf(Wout[k * 256 + n]);
}

// ---------------- QKV projection GEMM: A-resident full-K, n-loop inside ----------------
// block: 128 rows, K=256 resident; loops 6 n-tiles of 128. LDS = 64+64 KB.
__launch_bounds__(256, 1)
__global__ void proj_gemm(const float* __restrict__ x, const short* __restrict__ WcT,
                          const float* __restrict__ pos_emb,
                          short* __restrict__ Qb, short* __restrict__ Kb,
                          short* __restrict__ Vb) {
  __shared__ short As[128 * 256];
  __shared__ short Bs[128 * 256];
  const int t = threadIdx.x;
  const int m0 = blockIdx.x * 128;
  const int wave = t >> 6, lane = t & 63;
  const int wm = (wave & 1) * 64, wn = (wave >> 1) * 64;
  const int lr = lane & 15, g = lane >> 4;

  // stage A once: fp32 -> bf16, swizzled [row][k], row stride 512B
  for (int i = 0; i < 32; ++i) {
    int idx = t + i * 256;
    int row = idx >> 6, c4 = idx & 63;
    float4 vv = *reinterpret_cast<const float4*>(x + (size_t)(m0 + row) * 256 + c4 * 4);
    short4 pk;
    pk.x = f2bf(vv.x); pk.y = f2bf(vv.y); pk.z = f2bf(vv.z); pk.w = f2bf(vv.w);
    int byte = (row * 512 + c4 * 8) ^ ((row & 7) << 4);
    *reinterpret_cast<short4*>(reinterpret_cast<char*>(As) + byte) = pk;
  }

  for (int nt = 0; nt < 6; ++nt) {
    // stage B n-tile (full K)
    for (int i = 0; i < 16; ++i) {
      int idx = t + i * 256;
      int rn = idx >> 5, c = idx & 31;
      v8s vv = *reinterpret_cast<const v8s*>(WcT + (size_t)(nt * 128 + rn) * 256 + c * 8);
      int byte = (rn * 512 + c * 16) ^ ((rn & 7) << 4);
      *reinterpret_cast<v8s*>(reinterpret_cast<char*>(Bs) + byte) = vv;
    }
    __syncthreads();

    v4f acc[4][4];
#pragma unroll
    for (int i = 0; i < 4; ++i)
#pragma unroll
      for (int j = 0; j < 4; ++j) acc[i][j] = (v4f){0.f, 0.f, 0.f, 0.f};

    for (int ks = 0; ks < 8; ++ks) {
      v8s af[4], bfr[4];
#pragma unroll
      for (int i = 0; i < 4; ++i) {
        int row = wm + i * 16 + lr;
        int byte = (row * 512 + ks * 64 + g * 16) ^ ((row & 7) << 4);
        af[i] = *reinterpret_cast<const v8s*>(reinterpret_cast<const char*>(As) + byte);
      }
#pragma unroll
      for (int j = 0; j < 4; ++j) {
        int rn = wn + j * 16 + lr;
        int byte = (rn * 512 + ks * 64 + g * 16) ^ ((rn & 7) << 4);
        bfr[j] = *reinterpret_cast<const v8s*>(reinterpret_cast<const char*>(Bs) + byte);
      }
#pragma unroll
      for (int i = 0; i < 4; ++i)
#pragma unroll
        for (int j = 0; j < 4; ++j)
          acc[i][j] = __builtin_amdgcn_mfma_f32_16x16x32_bf16(af[i], bfr[j], acc[i][j], 0, 0, 0);
    }
    __syncthreads();

    // epilogue for this n-tile
#pragma unroll
    for (int i = 0; i < 4; ++i) {
#pragma unroll
      for (int j = 0; j < 4; ++j) {
        int colg = nt * 128 + wn + j * 16 + lr;   // global col in [0,768)
#pragma unroll
        for (int r = 0; r < 4; ++r) {
          int p = m0 + wm + i * 16 + g * 4 + r;
          float v = acc[i][j][r];
          if (nt < 2) {
            int yy = (p >> 7) & 127, xx = p & 127;
            int qi = (yy - min(max(yy, 2), 125) + 2) * 5 + (xx - min(max(xx, 2), 125) + 2);
            v += pos_emb[qi * 256 + colg];
            Qb[(size_t)p * 256 + colg] = f2bf(v);
          } else if (nt < 4) {
            Kb[(size_t)p * 256 + (colg - 256)] = f2bf(v);
          } else {
            Vb[(size_t)p * 256 + (colg - 512)] = f2bf(v);
          }
        }
      }
    }
  }
}

// ---------------- attention: fused online-softmax single pass ----------------
// thread = (position, head); block = 8y x 4x positions * 8 heads = 256 threads
// grid 1D 4096; batch -> XCD mapping via low 3 bits.
__launch_bounds__(256)
__global__ void attn_kernel(const short* __restrict__ Qb, const short* __restrict__ Kb,
                            const short* __restrict__ Vb, const float* __restrict__ pos_emb,
                            short* __restrict__ ACC) {
  __shared__ float pe[25 * 256];
  for (int i = threadIdx.x; i < 25 * 256; i += 256) {
    int f = i & 255;
    int dst = (i & ~255) + (f ^ ((f >> 5) << 2));  // bank-deconflict swizzle
    pe[dst] = pos_emb[i];
  }

  const int id = blockIdx.x;
  const int b = id & 7;            // batch -> XCD
  const int local = id >> 3;
  const int bx = local & 31, by = local >> 5;  // x-adjacent tiles consecutive in time
  const int t = threadIdx.x;
  const int h = t & 7, pi = t >> 3;
  const int xx = bx * 4 + (pi & 3);
  const int yy = by * 8 + (pi >> 2);
  const int yc = min(max(yy, 2), 125), xc = min(max(xx, 2), 125);
  const int hb = h * 32;
  const int hx4 = h << 2;
  const size_t pbase = ((size_t)((b * 128 + yy) * 128 + xx)) * 256 + hb;
  const float SCALE = 0.17677669529663689f;  // 1/sqrt(32)

  // load Q (issue before barrier; no LDS dependency)
  float q[32];
  {
    const v8s* qp = reinterpret_cast<const v8s*>(Qb + pbase);
#pragma unroll
    for (int c = 0; c < 4; ++c) {
      v8s qv = qp[c];
#pragma unroll
      for (int e = 0; e < 8; ++e) q[c * 8 + e] = bf2f(qv[e]);
    }
  }
  __syncthreads();

  // qpe[s] = dot(q, pe[s]) * scale  (hoists the per-offset pe add out of the K loop)
  float qpe[25];
#pragma unroll
  for (int s = 0; s < 25; ++s) {
    const float* peb = &pe[s * 256];
    float d = 0.f;
#pragma unroll
    for (int c = 0; c < 4; ++c) {
      float4 p0 = *reinterpret_cast<const float4*>(peb + ((hb + c * 8) ^ hx4));
      float4 p1 = *reinterpret_cast<const float4*>(peb + ((hb + c * 8 + 4) ^ hx4));
      d = fmaf(q[c * 8 + 0], p0.x, d);
      d = fmaf(q[c * 8 + 1], p0.y, d);
      d = fmaf(q[c * 8 + 2], p0.z, d);
      d = fmaf(q[c * 8 + 3], p0.w, d);
      d = fmaf(q[c * 8 + 4], p1.x, d);
      d = fmaf(q[c * 8 + 5], p1.y, d);
      d = fmaf(q[c * 8 + 6], p1.z, d);
      d = fmaf(q[c * 8 + 7], p1.w, d);
    }
    qpe[s] = d * SCALE;
  }

  // single online pass: scores are O(1) magnitude -> no max subtraction needed
  float l = 0.f;
  float oa[32];
#pragma unroll
  for (int f = 0; f < 32; ++f) oa[f] = 0.f;

#pragma unroll
  for (int s = 0; s < 25; ++s) {
    const int ny = yc + s / 5 - 2, nx = xc + s % 5 - 2;
    const size_t nb = ((size_t)((b * 128 + ny) * 128 + nx)) * 256 + hb;
    const v8s* kp = reinterpret_cast<const v8s*>(Kb + nb);
    const v8s* vp = reinterpret_cast<const v8s*>(Vb + nb);
    v8s k0 = kp[0], k1 = kp[1], k2 = kp[2], k3 = kp[3];
    v8s v0 = vp[0], v1 = vp[1], v2 = vp[2], v3 = vp[3];
    float dot = 0.f;
#pragma unroll
    for (int e = 0; e < 8; ++e) dot = fmaf(q[e], bf2f(k0[e]), dot);
#pragma unroll
    for (int e = 0; e < 8; ++e) dot = fmaf(q[8 + e], bf2f(k1[e]), dot);
#pragma unroll
    for (int e = 0; e < 8; ++e) dot = fmaf(q[16 + e], bf2f(k2[e]), dot);
#pragma unroll
    for (int e = 0; e < 8; ++e) dot = fmaf(q[24 + e], bf2f(k3[e]), dot);
    float w = __expf(fmaf(dot, SCALE, qpe[s]));
    l += w;
#pragma unroll
    for (int e = 0; e < 8; ++e) oa[e] = fmaf(w, bf2f(v0[e]), oa[e]);
#pragma unroll
    for (int e = 0; e < 8; ++e) oa[8 + e] = fmaf(w, bf2f(v1[e]), oa[8 + e]);
#pragma unroll
    for (int e = 0; e < 8; ++e) oa[16 + e] = fmaf(w, bf2f(v2[e]), oa[16 + e]);
#pragma unroll
    for (int e = 0; e < 8; ++e) oa[24 + e] = fmaf(w, bf2f(v3[e]), oa[24 + e]);
  }

  float inv = 1.f / l;
  v8s* op = reinterpret_cast<v8s*>(ACC + pbase);
#pragma unroll
  for (int c = 0; c < 4; ++c) {
    v8s pk;
#pragma unroll
    for (int e = 0; e < 8; ++e) pk[e] = f2bf(oa[c * 8 + e] * inv);
    op[c] = pk;
  }
}

// ---------------- output projection GEMM: A-resident full-K, 2 n-tiles ----------------
__launch_bounds__(256, 1)
__global__ void out_gemm(const short* __restrict__ A, const short* __restrict__ WoT,
                         float* __restrict__ out) {
  __shared__ short As[128 * 256];
  __shared__ short Bs[128 * 256];
  const int t = threadIdx.x;
  const int m0 = blockIdx.x * 128;
  const int wave = t >> 6, lane = t & 63;
  const int wm = (wave & 1) * 64, wn = (wave >> 1) * 64;
  const int lr = lane & 15, g = lane >> 4;

  for (int i = 0; i < 16; ++i) {
    int idx = t + i * 256;
    int rn = idx >> 5, c = idx & 31;
    v8s vv = *reinterpret_cast<const v8s*>(A + (size_t)(m0 + rn) * 256 + c * 8);
    int byte = (rn * 512 + c * 16) ^ ((rn & 7) << 4);
    *reinterpret_cast<v8s*>(reinterpret_cast<char*>(As) + byte) = vv;
  }

  for (int nt = 0; nt < 2; ++nt) {
    for (int i = 0; i < 16; ++i) {
      int idx = t + i * 256;
      int rn = idx >> 5, c = idx & 31;
      v8s vv = *reinterpret_cast<const v8s*>(WoT + (size_t)(nt * 128 + rn) * 256 + c * 8);
      int byte = (rn * 512 + c * 16) ^ ((rn & 7) << 4);
      *reinterpret_cast<v8s*>(reinterpret_cast<char*>(Bs) + byte) = vv;
    }
    __syncthreads();

    v4f acc[4][4];
#pragma unroll
    for (int i = 0; i < 4; ++i)
#pragma unroll
      for (int j = 0; j < 4; ++j) acc[i][j] = (v4f){0.f, 0.f, 0.f, 0.f};

    for (int ks = 0; ks < 8; ++ks) {
      v8s af[4], bfr[4];
#pragma unroll
      for (int i = 0; i < 4; ++i) {
        int row = wm + i * 16 + lr;
        int byte = (row * 512 + ks * 64 + g * 16) ^ ((row & 7) << 4);
        af[i] = *reinterpret_cast<const v8s*>(reinterpret_cast<const char*>(As) + byte);
      }
#pragma unroll
      for (int j = 0; j < 4; ++j) {
        int rn = wn + j * 16 + lr;
        int byte = (rn * 512 + ks * 64 + g * 16) ^ ((rn & 7) << 4);
        bfr[j] = *reinterpret_cast<const v8s*>(reinterpret_cast<const char*>(Bs) + byte);
      }
#pragma unroll
      for (int i = 0; i < 4; ++i)
#pragma unroll
        for (int j = 0; j < 4; ++j)
          acc[i][j] = __builtin_amdgcn_mfma_f32_16x16x32_bf16(af[i], bfr[j], acc[i][j], 0, 0, 0);
    }
    __syncthreads();

#pragma unroll
    for (int i = 0; i < 4; ++i) {
#pragma unroll
      for (int j = 0; j < 4; ++j) {
        int colg = nt * 128 + wn + j * 16 + lr;
#pragma unroll
        for (int r = 0; r < 4; ++r) {
          int p = m0 + wm + i * 16 + g * 4 + r;
          out[(size_t)p * 256 + colg] = acc[i][j][r];
        }
      }
    }
  }
}

extern "C" void kernel_launch(void* const* d_in, const int* in_sizes, int n_in,
                              void* d_out, int out_size, void* d_ws, size_t ws_size,
                              hipStream_t stream) {
  const float* x       = (const float*)d_in[0];
  const float* Wq      = (const float*)d_in[1];
  const float* Wk      = (const float*)d_in[2];
  const float* Wv      = (const float*)d_in[3];
  const float* Wout    = (const float*)d_in[4];
  const float* pos_emb = (const float*)d_in[5];
  float* out = (float*)d_out;

  char* ws = (char*)d_ws;
  short* WcT  = (short*)ws;                       // 768*256*2   = 393216 B
  short* WoT  = (short*)(ws + 393216);            // 256*256*2   = 131072 B
  short* Qb   = (short*)(ws + 524288);            // 131072*256*2 each
  short* Kb   = Qb + (size_t)131072 * 256;
  short* Vb   = Kb + (size_t)131072 * 256;
  short* ACCb = Vb + (size_t)131072 * 256;

  prep_weights<<<768, 256, 0, stream>>>(Wq, Wk, Wv, Wout, WcT, WoT);
  proj_gemm<<<1024, 256, 0, stream>>>(x, WcT, pos_emb, Qb, Kb, Vb);
  attn_kernel<<<4096, 256, 0, stream>>>(Qb, Kb, Vb, pos_emb, ACCb);
  out_gemm<<<1024, 256, 0, stream>>>(ACCb, WoT, out);
}